// Round 7
// baseline (121.082 us; speedup 1.0000x reference)
//
#include <hip/hip_runtime.h>
#include <hip/hip_bf16.h>

#define N_NODES 50000
#define K_EIG   512
#define F_DIM   128
#define NPAD    51200     // 200 splits * 256
#define NSPLITS 200
#define CHUNK   256

typedef __attribute__((ext_vector_type(8))) short bf16x8;
typedef __attribute__((ext_vector_type(4))) short s16x4;
typedef __attribute__((ext_vector_type(4))) float f32x4;
typedef __attribute__((ext_vector_type(2))) unsigned u32x2;

static __device__ __forceinline__ unsigned pk2(float lo, float hi) {
    unsigned short a = __builtin_bit_cast(unsigned short, __float2bfloat16(lo));
    unsigned short b = __builtin_bit_cast(unsigned short, __float2bfloat16(hi));
    return ((unsigned)b << 16) | (unsigned)a;
}

static __device__ __forceinline__ short f2bf(float f) {
    union { float f; unsigned u; } v; v.f = f;
    unsigned r = v.u + 0x7fffu + ((v.u >> 16) & 1u);   // RNE
    return (short)(r >> 16);
}

static __device__ __forceinline__ float bf2f(unsigned short u) {
    union { unsigned u; float f; } v; v.u = ((unsigned)u) << 16;
    return v.f;
}

// ---------------- prep: x -> xT[f][n(pad)] bf16 ------------------------------
__global__ __launch_bounds__(256) void prep_x(const float* __restrict__ x,
                                              unsigned* __restrict__ xT)
{
    const int n0 = blockIdx.x * 64;
    const int f0 = blockIdx.y * 64;
    const int a  = threadIdx.x & 15;
    const int b  = threadIdx.x >> 4;
    const int n  = n0 + 4 * a;
    const int f  = f0 + 4 * b;

    float r[4][4];
    #pragma unroll
    for (int j = 0; j < 4; ++j) {
        int nr = n + j;
        if (nr < N_NODES) {
            f32x4 v = *reinterpret_cast<const f32x4*>(x + (long)nr * F_DIM + f);
            r[j][0] = v[0]; r[j][1] = v[1]; r[j][2] = v[2]; r[j][3] = v[3];
        } else {
            r[j][0] = r[j][1] = r[j][2] = r[j][3] = 0.f;
        }
    }
    #pragma unroll
    for (int i = 0; i < 4; ++i) {
        unsigned* p = xT + ((long)(f + i) * NPAD + n) / 2;
        p[0] = pk2(r[0][i], r[1][i]);
        p[1] = pk2(r[2][i], r[3][i]);
    }
}

// ---------------- fused GEMM1: pipelined LDS-transpose + MFMA + Ubf ----------
// partial[split][f][k0:64] = sum_n U[n][k]*x[n][f];  Ubf[n][k] = bf16(U[n][k]).
// grid (8 kt, 200 splits). Double-buffered LDS (one barrier/step); next-step
// U tile + B frags register-prefetched so HBM latency hides under work.
__global__ __launch_bounds__(256) void k_spec_f(
    const float* __restrict__ U, const unsigned short* __restrict__ xT,
    unsigned* __restrict__ Ubf, unsigned short* __restrict__ partial)
{
    __shared__ unsigned char lds[2][64 * 128];   // 16 KB

    const int kt    = blockIdx.x;
    const int split = blockIdx.y;
    const int tid   = threadIdx.x;
    const int wid   = tid >> 6;
    const int lane  = tid & 63;
    const int h     = lane >> 4;
    const int m     = lane & 15;
    const int k0    = kt * 64;
    const int f0    = wid * 32;
    const int nbeg  = split * CHUNK;

    const int kq = tid & 15;    // k-quad: k_local = 4*kq (coalesced U/Ubf rows)
    const int nq = tid >> 4;    // n-quad: n_local = 4*nq

    f32x4 acc[4][2];
    #pragma unroll
    for (int s = 0; s < 4; ++s)
        #pragma unroll
        for (int t = 0; t < 2; ++t)
            #pragma unroll
            for (int e = 0; e < 4; ++e) acc[s][t][e] = 0.f;

    const unsigned short* Bbase = xT + (long)(f0 + m) * NPAD + 8 * h;

    float  r[4][4];
    bf16x8 bfr[2][2];

    // ---- prologue: load step-0 U tile + B frags ----
    #pragma unroll
    for (int j = 0; j < 4; ++j) {
        int n = nbeg + 4 * nq + j;
        if (n < N_NODES) {
            f32x4 v = *reinterpret_cast<const f32x4*>(U + (long)n * K_EIG + k0 + 4 * kq);
            r[j][0] = v[0]; r[j][1] = v[1]; r[j][2] = v[2]; r[j][3] = v[3];
        } else {
            r[j][0] = r[j][1] = r[j][2] = r[j][3] = 0.f;
        }
    }
    #pragma unroll
    for (int sub = 0; sub < 2; ++sub)
        #pragma unroll
        for (int t = 0; t < 2; ++t)
            bfr[sub][t] = *reinterpret_cast<const bf16x8*>(
                Bbase + (long)16 * t * NPAD + nbeg + 32 * sub);

    #pragma unroll
    for (int step = 0; step < 4; ++step) {
        const int ntile = nbeg + 64 * step;
        const int buf   = step & 1;

        // ---- prefetch next step (overlaps everything below) ----
        float  rN[4][4];
        bf16x8 bN[2][2];
        if (step < 3) {
            const int nt2 = ntile + 64;
            #pragma unroll
            for (int j = 0; j < 4; ++j) {
                int n = nt2 + 4 * nq + j;
                if (n < N_NODES) {
                    f32x4 v = *reinterpret_cast<const f32x4*>(
                        U + (long)n * K_EIG + k0 + 4 * kq);
                    rN[j][0] = v[0]; rN[j][1] = v[1]; rN[j][2] = v[2]; rN[j][3] = v[3];
                } else {
                    rN[j][0] = rN[j][1] = rN[j][2] = rN[j][3] = 0.f;
                }
            }
            #pragma unroll
            for (int sub = 0; sub < 2; ++sub)
                #pragma unroll
                for (int t = 0; t < 2; ++t)
                    bN[sub][t] = *reinterpret_cast<const bf16x8*>(
                        Bbase + (long)16 * t * NPAD + nt2 + 32 * sub);
        }

        // ---- Ubf side-product (8B stores, 128B-coalesced across kq) ----
        #pragma unroll
        for (int j = 0; j < 4; ++j) {
            int n = ntile + 4 * nq + j;
            if (n < N_NODES) {
                u32x2 w; w[0] = pk2(r[j][0], r[j][1]); w[1] = pk2(r[j][2], r[j][3]);
                *reinterpret_cast<u32x2*>(Ubf + ((long)n * K_EIG + k0 + 4 * kq) / 2) = w;
            }
        }

        // ---- micro-transpose to LDS buf [k][n] bf16, XOR-swizzled ----
        #pragma unroll
        for (int i = 0; i < 4; ++i) {
            int kl = 4 * kq + i;
            unsigned lo = pk2(r[0][i], r[1][i]);
            unsigned hi = pk2(r[2][i], r[3][i]);
            int byte = (kl * 128 + 8 * nq) ^ ((kl & 7) << 4);
            *reinterpret_cast<unsigned long long*>(&lds[buf][byte]) =
                ((unsigned long long)hi << 32) | (unsigned long long)lo;
        }
        __syncthreads();   // tile ready (and prev-prev buffer reads long done)

        // ---- consume: ds_read A frags + MFMA ----
        #pragma unroll
        for (int sub = 0; sub < 2; ++sub) {
            bf16x8 af[4];
            #pragma unroll
            for (int s = 0; s < 4; ++s) {
                int row  = 16 * s + m;
                int byte = (row * 128 + 64 * sub + 16 * h) ^ ((m & 7) << 4);
                af[s] = *reinterpret_cast<const bf16x8*>(&lds[buf][byte]);
            }
            #pragma unroll
            for (int s = 0; s < 4; ++s)
                #pragma unroll
                for (int t = 0; t < 2; ++t)
                    acc[s][t] = __builtin_amdgcn_mfma_f32_16x16x32_bf16(
                        af[s], bfr[sub][t], acc[s][t], 0, 0, 0);
        }

        // ---- rotate ----
        if (step < 3) {
            #pragma unroll
            for (int j = 0; j < 4; ++j)
                #pragma unroll
                for (int i = 0; i < 4; ++i) r[j][i] = rN[j][i];
            #pragma unroll
            for (int sub = 0; sub < 2; ++sub)
                #pragma unroll
                for (int t = 0; t < 2; ++t) bfr[sub][t] = bN[sub][t];
        }
    }

    unsigned short* pbase = partial + (long)split * (F_DIM * K_EIG);
    #pragma unroll
    for (int s = 0; s < 4; ++s)
        #pragma unroll
        for (int t = 0; t < 2; ++t) {
            int k = k0 + 16 * s + 4 * h;
            int f = f0 + 16 * t + m;
            s16x4 v;
            #pragma unroll
            for (int rr = 0; rr < 4; ++rr) v[rr] = f2bf(acc[s][t][rr]);
            *reinterpret_cast<s16x4*>(pbase + (long)f * K_EIG + k) = v;
        }
}

// ---------------- reduce partials, fold g, emit bf16 spec --------------------
__global__ __launch_bounds__(256) void k_reduce(
    const unsigned short* __restrict__ partial, const float* __restrict__ g,
    unsigned short* __restrict__ specbf)
{
    int idx = blockIdx.x * 256 + threadIdx.x;   // 0..65535
    float s = 0.f;
    #pragma unroll 8
    for (int p = 0; p < NSPLITS; ++p)
        s += bf2f(partial[(long)p * (F_DIM * K_EIG) + idx]);
    int k = idx & (K_EIG - 1);
    specbf[idx] = (unsigned short)f2bf(s * g[k]);
}

// ---------------- GEMM2: out = relu(Ubf @ specbf^T), reg double-buffered -----
__global__ __launch_bounds__(256) void k_out_bf(
    const unsigned short* __restrict__ Ubf,
    const unsigned short* __restrict__ specbf,
    float* __restrict__ out)
{
    const int tid  = threadIdx.x;
    const int wid  = tid >> 6;
    const int lane = tid & 63;
    const int h = lane >> 4, m = lane & 15;
    const int wr = wid >> 1, wc = wid & 1;
    const int nbase = blockIdx.x * 64 + wr * 32;
    const int fbase = wc * 64;

    const unsigned short* Arow[2];
    #pragma unroll
    for (int i = 0; i < 2; ++i) {
        int n  = nbase + 16 * i + m;
        int nc = (n < N_NODES) ? n : (N_NODES - 1);
        Arow[i] = Ubf + (long)nc * K_EIG + 8 * h;
    }
    const unsigned short* Brow = specbf + (long)(fbase + m) * K_EIG + 8 * h;

    f32x4 acc[2][4];
    #pragma unroll
    for (int i = 0; i < 2; ++i)
        #pragma unroll
        for (int t = 0; t < 4; ++t)
            #pragma unroll
            for (int e = 0; e < 4; ++e) acc[i][t][e] = 0.f;

    bf16x8 aC[2], bC[4];
    #pragma unroll
    for (int i = 0; i < 2; ++i)
        aC[i] = *reinterpret_cast<const bf16x8*>(Arow[i]);
    #pragma unroll
    for (int t = 0; t < 4; ++t)
        bC[t] = *reinterpret_cast<const bf16x8*>(Brow + (long)16 * t * K_EIG);

    for (int kb = 0; kb < K_EIG; kb += 32) {
        int kn = (kb + 32 < K_EIG) ? kb + 32 : 0;   // clamp; last-iter load unused
        bf16x8 aN[2], bN[4];
        #pragma unroll
        for (int i = 0; i < 2; ++i)
            aN[i] = *reinterpret_cast<const bf16x8*>(Arow[i] + kn);
        #pragma unroll
        for (int t = 0; t < 4; ++t)
            bN[t] = *reinterpret_cast<const bf16x8*>(Brow + (long)16 * t * K_EIG + kn);

        #pragma unroll
        for (int i = 0; i < 2; ++i)
            #pragma unroll
            for (int t = 0; t < 4; ++t)
                acc[i][t] = __builtin_amdgcn_mfma_f32_16x16x32_bf16(
                    aC[i], bC[t], acc[i][t], 0, 0, 0);

        #pragma unroll
        for (int i = 0; i < 2; ++i) aC[i] = aN[i];
        #pragma unroll
        for (int t = 0; t < 4; ++t) bC[t] = bN[t];
    }

    #pragma unroll
    for (int i = 0; i < 2; ++i)
        #pragma unroll
        for (int r = 0; r < 4; ++r) {
            int nn = nbase + 16 * i + 4 * h + r;
            if (nn < N_NODES) {
                float* orow = out + (long)nn * F_DIM + fbase + m;
                #pragma unroll
                for (int t = 0; t < 4; ++t)
                    orow[16 * t] = fmaxf(acc[i][t][r], 0.f);
            }
        }
}

// =================== deep fallback (round-1) if ws tiny ======================
__global__ __launch_bounds__(256) void k_spec_v1(
    const float* __restrict__ U, const float* __restrict__ g,
    const float* __restrict__ x, float* __restrict__ specT)
{
    const int kt    = blockIdx.x;
    const int split = blockIdx.y;
    const int tid   = threadIdx.x;
    const int wid   = tid >> 6;
    const int lane  = tid & 63;
    const int h     = lane >> 4;
    const int m     = lane & 15;
    const int k0 = kt * 64;
    const int f0 = wid * 32;
    const int chunk1 = 782;
    const int n_start = split * chunk1;
    int n_end = n_start + chunk1;
    if (n_end > N_NODES) n_end = N_NODES;

    f32x4 acc[4][2];
    #pragma unroll
    for (int s = 0; s < 4; ++s)
        #pragma unroll
        for (int t = 0; t < 2; ++t)
            #pragma unroll
            for (int e = 0; e < 4; ++e) acc[s][t][e] = 0.f;

    for (int nb = n_start; nb < n_end; nb += 32) {
        bf16x8 a[4]; bf16x8 b[2];
        const int nrow = nb + 8 * h;
        #pragma unroll
        for (int j = 0; j < 8; ++j) {
            int nn = nrow + j;
            bool valid = (nn < n_end);
            int nc = valid ? nn : (n_end - 1);
            const float* Urow = U + (long)nc * K_EIG + k0 + m;
            const float* Xrow = x + (long)nc * F_DIM + f0 + m;
            #pragma unroll
            for (int s = 0; s < 4; ++s) {
                short bv = f2bf(Urow[16 * s]);
                a[s][j] = valid ? bv : (short)0;
            }
            #pragma unroll
            for (int t = 0; t < 2; ++t) {
                short bv = f2bf(Xrow[16 * t]);
                b[t][j] = valid ? bv : (short)0;
            }
        }
        #pragma unroll
        for (int s = 0; s < 4; ++s)
            #pragma unroll
            for (int t = 0; t < 2; ++t)
                acc[s][t] = __builtin_amdgcn_mfma_f32_16x16x32_bf16(
                    a[s], b[t], acc[s][t], 0, 0, 0);
    }
    #pragma unroll
    for (int s = 0; s < 4; ++s)
        #pragma unroll
        for (int t = 0; t < 2; ++t)
            #pragma unroll
            for (int r = 0; r < 4; ++r) {
                int k = k0 + 16 * s + 4 * h + r;
                int f = f0 + 16 * t + m;
                atomicAdd(&specT[(long)f * K_EIG + k], acc[s][t][r] * g[k]);
            }
}

__global__ __launch_bounds__(256) void k_out_v1(
    const float* __restrict__ U, const float* __restrict__ specT,
    float* __restrict__ out)
{
    const int tid  = threadIdx.x;
    const int wid  = tid >> 6;
    const int lane = tid & 63;
    const int h = lane >> 4, m = lane & 15;
    const int wr = wid >> 1, wc = wid & 1;
    const int nbase = blockIdx.x * 128 + wr * 64;
    const int fbase = wc * 64;

    f32x4 acc[4][4];
    #pragma unroll
    for (int i = 0; i < 4; ++i)
        #pragma unroll
        for (int t = 0; t < 4; ++t)
            #pragma unroll
            for (int e = 0; e < 4; ++e) acc[i][t][e] = 0.f;

    for (int kb = 0; kb < K_EIG; kb += 32) {
        bf16x8 a[4], b[4];
        #pragma unroll
        for (int i = 0; i < 4; ++i) {
            int nn = nbase + 16 * i + m;
            bool valid = (nn < N_NODES);
            int nc = valid ? nn : (N_NODES - 1);
            const f32x4* p = reinterpret_cast<const f32x4*>(
                U + (long)nc * K_EIG + kb + 8 * h);
            f32x4 lo = p[0], hi = p[1];
            #pragma unroll
            for (int j = 0; j < 4; ++j) {
                short b0 = f2bf(lo[j]), b1 = f2bf(hi[j]);
                a[i][j]     = valid ? b0 : (short)0;
                a[i][j + 4] = valid ? b1 : (short)0;
            }
        }
        #pragma unroll
        for (int t = 0; t < 4; ++t) {
            const f32x4* p = reinterpret_cast<const f32x4*>(
                specT + (long)(fbase + 16 * t + m) * K_EIG + kb + 8 * h);
            f32x4 lo = p[0], hi = p[1];
            #pragma unroll
            for (int j = 0; j < 4; ++j) {
                b[t][j]     = f2bf(lo[j]);
                b[t][j + 4] = f2bf(hi[j]);
            }
        }
        #pragma unroll
        for (int i = 0; i < 4; ++i)
            #pragma unroll
            for (int t = 0; t < 4; ++t)
                acc[i][t] = __builtin_amdgcn_mfma_f32_16x16x32_bf16(
                    a[i], b[t], acc[i][t], 0, 0, 0);
    }
    #pragma unroll
    for (int i = 0; i < 4; ++i)
        #pragma unroll
        for (int r = 0; r < 4; ++r) {
            int nn = nbase + 16 * i + 4 * h + r;
            if (nn < N_NODES) {
                float* orow = out + (long)nn * F_DIM + fbase + m;
                #pragma unroll
                for (int t = 0; t < 4; ++t)
                    orow[16 * t] = fmaxf(acc[i][t][r], 0.f);
            }
        }
}

// ============================================================================
extern "C" void kernel_launch(void* const* d_in, const int* in_sizes, int n_in,
                              void* d_out, int out_size, void* d_ws, size_t ws_size,
                              hipStream_t stream) {
    const float* U = (const float*)d_in[0];
    const float* g = (const float*)d_in[1];
    const float* x = (const float*)d_in[2];
    float* out = (float*)d_out;

    // ws layout (bytes)
    const size_t OFF_XT    = 0;                 // 128*51200*2   = 13,107,200
    const size_t OFF_PART  = 13107200;          // 200*128*512*2 = 26,214,400
    const size_t OFF_SPECB = 39321600;          // 128*512*2     =    131,072
    const size_t OFF_UBF   = 39452672;          // 50000*512*2   = 51,200,000
    const size_t WS_NEEDED = 90652672;

    if (ws_size >= WS_NEEDED) {
        unsigned*       xT     = (unsigned*)((char*)d_ws + OFF_XT);
        unsigned short* part   = (unsigned short*)((char*)d_ws + OFF_PART);
        unsigned short* specbf = (unsigned short*)((char*)d_ws + OFF_SPECB);
        unsigned*       Ubf    = (unsigned*)((char*)d_ws + OFF_UBF);

        dim3 gx(NPAD / 64, F_DIM / 64);   // 800 x 2
        prep_x<<<gx, 256, 0, stream>>>(x, xT);

        dim3 g1(K_EIG / 64, NSPLITS);     // 8 x 200 = 1600 blocks
        k_spec_f<<<g1, 256, 0, stream>>>(U, (const unsigned short*)xT,
                                         Ubf, part);

        k_reduce<<<(K_EIG * F_DIM) / 256, 256, 0, stream>>>(part, g, specbf);

        int nb2 = (N_NODES + 63) / 64;    // 782
        k_out_bf<<<nb2, 256, 0, stream>>>((const unsigned short*)Ubf,
                                          specbf, out);
    } else {
        float* specT = (float*)d_ws;      // 256 KB
        hipMemsetAsync(specT, 0, (size_t)K_EIG * F_DIM * sizeof(float), stream);
        dim3 g1(K_EIG / 64, 64);
        k_spec_v1<<<g1, 256, 0, stream>>>(U, g, x, specT);
        int nb2 = (N_NODES + 127) / 128;
        k_out_v1<<<nb2, 256, 0, stream>>>(U, specT, out);
    }
}

// Round 9
// 95.267 us; speedup vs baseline: 1.2710x; 1.2710x over previous
//
#include <hip/hip_runtime.h>
#include <hip/hip_bf16.h>

#define N_NODES 50000
#define K_EIG   512
#define F_DIM   128
#define NPAD    51200     // 200 splits * 256
#define NSPLITS 200
#define CHUNK   256
#define NT16    3136      // Ubfa n-tiles (covers 50176, pad >= 50000/16=3125)

typedef __attribute__((ext_vector_type(8))) short bf16x8;
typedef __attribute__((ext_vector_type(4))) short s16x4;
typedef __attribute__((ext_vector_type(4))) float f32x4;
typedef __attribute__((ext_vector_type(2))) unsigned u32x2;

static __device__ __forceinline__ unsigned pk2(float lo, float hi) {
    unsigned short a = __builtin_bit_cast(unsigned short, __float2bfloat16(lo));
    unsigned short b = __builtin_bit_cast(unsigned short, __float2bfloat16(hi));
    return ((unsigned)b << 16) | (unsigned)a;
}

static __device__ __forceinline__ short f2bf(float f) {
    union { float f; unsigned u; } v; v.f = f;
    unsigned r = v.u + 0x7fffu + ((v.u >> 16) & 1u);   // RNE
    return (short)(r >> 16);
}

static __device__ __forceinline__ float bf2f(unsigned short u) {
    union { unsigned u; float f; } v; v.u = ((unsigned)u) << 16;
    return v.f;
}

// ---------------- prep: x -> xTa fragment-ready ------------------------------
// xTa[ft16(8)][nt32(1600)][lane(64)][8]: xTa[ft][nt][16h+m][j] = x[nt*32+8h+j][ft*16+m]
__global__ __launch_bounds__(256) void prep_x(const float* __restrict__ x,
                                              unsigned short* __restrict__ xTa)
{
    const int n0 = blockIdx.x * 64;
    const int f0 = blockIdx.y * 64;
    const int fa = threadIdx.x & 15;
    const int nb = threadIdx.x >> 4;
    const int n  = n0 + 4 * nb;
    const int f  = f0 + 4 * fa;

    float r[4][4];
    #pragma unroll
    for (int jj = 0; jj < 4; ++jj) {
        int nr = n + jj;
        if (nr < N_NODES) {
            f32x4 v = *reinterpret_cast<const f32x4*>(x + (long)nr * F_DIM + f);
            r[jj][0] = v[0]; r[jj][1] = v[1]; r[jj][2] = v[2]; r[jj][3] = v[3];
        } else {
            r[jj][0] = r[jj][1] = r[jj][2] = r[jj][3] = 0.f;
        }
    }
    const int nt32 = n >> 5;
    const int hpart = ((n >> 3) & 3) * 16;      // 16*((n%32)/8)
    const int slot  = 4 * (nb & 1);             // n%8 in {0,4}
    #pragma unroll
    for (int i = 0; i < 4; ++i) {
        int fi = f + i;
        size_t ad = ((size_t)((fi >> 4) * 1600 + nt32) * 64 + hpart + (fi & 15)) * 8 + slot;
        u32x2 w; w[0] = pk2(r[0][i], r[1][i]); w[1] = pk2(r[2][i], r[3][i]);
        *reinterpret_cast<u32x2*>(xTa + ad) = w;
    }
}

// ---------------- fused GEMM1 + Ubfa production ------------------------------
// part2[kt][split][tid][32] = per-thread acc fragments (bf16).
// Ubfa[nt16][kt32][lane][8]: Ubfa[nt][kt][16h+m][j] = bf16(U[nt*16+m][kt*32+8h+j])
__global__ __launch_bounds__(256) void k_spec_f(
    const float* __restrict__ U, const unsigned short* __restrict__ xTa,
    unsigned short* __restrict__ Ubfa, unsigned short* __restrict__ part2)
{
    __shared__ unsigned char lds1[2][64 * 128];   // [k][n] bf16, swizzled (A-frags)
    __shared__ unsigned char lds2[2][64 * 128];   // [n][k] bf16, swizzled (Ubfa frags)

    const int kt    = blockIdx.x;      // 0..7
    const int split = blockIdx.y;      // 0..199
    const int tid   = threadIdx.x;
    const int wid   = tid >> 6;
    const int lane  = tid & 63;
    const int h     = lane >> 4;
    const int m     = lane & 15;
    const int k0    = kt * 64;
    const int nbeg  = split * CHUNK;

    const int kq = tid & 15;    // k-quad (coalesced U reads)
    const int nq = tid >> 4;    // n-quad

    f32x4 acc[4][2];
    #pragma unroll
    for (int s = 0; s < 4; ++s)
        #pragma unroll
        for (int t = 0; t < 2; ++t)
            #pragma unroll
            for (int e = 0; e < 4; ++e) acc[s][t][e] = 0.f;

    // B fragment loads: 16B per lane, wave-contiguous 1KB
    const unsigned short* Bl = xTa + (size_t)lane * 8;
    const int ftb = wid * 2;   // ft16 base for this wave (f0 = wid*32)

    float  r[4][4];
    bf16x8 bfr[2][2];

    // ---- prologue: step-0 U tile + B frags ----
    #pragma unroll
    for (int j = 0; j < 4; ++j) {
        int n = nbeg + 4 * nq + j;
        if (n < N_NODES) {
            f32x4 v = *reinterpret_cast<const f32x4*>(U + (long)n * K_EIG + k0 + 4 * kq);
            r[j][0] = v[0]; r[j][1] = v[1]; r[j][2] = v[2]; r[j][3] = v[3];
        } else {
            r[j][0] = r[j][1] = r[j][2] = r[j][3] = 0.f;
        }
    }
    #pragma unroll
    for (int sub = 0; sub < 2; ++sub)
        #pragma unroll
        for (int t = 0; t < 2; ++t)
            bfr[sub][t] = *reinterpret_cast<const bf16x8*>(
                Bl + (size_t)((ftb + t) * 1600 + (nbeg >> 5) + sub) * 512);

    #pragma unroll
    for (int step = 0; step < 4; ++step) {
        const int ntile = nbeg + 64 * step;
        const int buf   = step & 1;

        // ---- prefetch next step ----
        float  rN[4][4];
        bf16x8 bN[2][2];
        if (step < 3) {
            const int nt2 = ntile + 64;
            #pragma unroll
            for (int j = 0; j < 4; ++j) {
                int n = nt2 + 4 * nq + j;
                if (n < N_NODES) {
                    f32x4 v = *reinterpret_cast<const f32x4*>(
                        U + (long)n * K_EIG + k0 + 4 * kq);
                    rN[j][0] = v[0]; rN[j][1] = v[1]; rN[j][2] = v[2]; rN[j][3] = v[3];
                } else {
                    rN[j][0] = rN[j][1] = rN[j][2] = rN[j][3] = 0.f;
                }
            }
            #pragma unroll
            for (int sub = 0; sub < 2; ++sub)
                #pragma unroll
                for (int t = 0; t < 2; ++t)
                    bN[sub][t] = *reinterpret_cast<const bf16x8*>(
                        Bl + (size_t)((ftb + t) * 1600 + (nt2 >> 5) + sub) * 512);
        }

        // ---- LDS1: transpose [k][n], byte ^= (k&7)<<4 ----
        #pragma unroll
        for (int i = 0; i < 4; ++i) {
            int kl = 4 * kq + i;
            unsigned lo = pk2(r[0][i], r[1][i]);
            unsigned hi = pk2(r[2][i], r[3][i]);
            int byte = (kl * 128 + 8 * nq) ^ ((kl & 7) << 4);
            *reinterpret_cast<unsigned long long*>(&lds1[buf][byte]) =
                ((unsigned long long)hi << 32) | (unsigned long long)lo;
        }
        // ---- LDS2: row-copy [n][k], byte ^= (n&7)<<4 ----
        #pragma unroll
        for (int j = 0; j < 4; ++j) {
            int nl = 4 * nq + j;
            unsigned lo = pk2(r[j][0], r[j][1]);
            unsigned hi = pk2(r[j][2], r[j][3]);
            int byte = (nl * 128 + 8 * kq) ^ ((nl & 7) << 4);
            *reinterpret_cast<unsigned long long*>(&lds2[buf][byte]) =
                ((unsigned long long)hi << 32) | (unsigned long long)lo;
        }
        __syncthreads();

        // ---- MFMA: A frags from LDS1 ----
        #pragma unroll
        for (int sub = 0; sub < 2; ++sub) {
            bf16x8 af[4];
            #pragma unroll
            for (int s = 0; s < 4; ++s) {
                int row  = 16 * s + m;
                int byte = (row * 128 + 64 * sub + 16 * h) ^ ((m & 7) << 4);
                af[s] = *reinterpret_cast<const bf16x8*>(&lds1[buf][byte]);
            }
            #pragma unroll
            for (int s = 0; s < 4; ++s)
                #pragma unroll
                for (int t = 0; t < 2; ++t)
                    acc[s][t] = __builtin_amdgcn_mfma_f32_16x16x32_bf16(
                        af[s], bfr[sub][t], acc[s][t], 0, 0, 0);
        }

        // ---- Ubfa fragment stores (coalesced 16B/lane) from LDS2 ----
        {
            const int fid = tid >> 5;       // 0..7: fragment (ntl, ktl)
            const int q   = tid & 31;
            const int ntl = fid >> 1;
            const int ktl = fid & 1;
            if (ntile + ntl * 16 < N_NODES) {
                #pragma unroll
                for (int e = 0; e < 2; ++e) {
                    int l    = 2 * q + e;
                    int row  = ntl * 16 + (l & 15);
                    int byte = (row * 128 + ktl * 64 + 16 * (l >> 4)) ^ ((row & 7) << 4);
                    bf16x8 v = *reinterpret_cast<const bf16x8*>(&lds2[buf][byte]);
                    size_t ad = (((size_t)(ntile >> 4) + ntl) * 16 + (kt * 2 + ktl)) * 64 + l;
                    *reinterpret_cast<bf16x8*>(Ubfa + ad * 8) = v;
                }
            }
        }

        // ---- rotate ----
        if (step < 3) {
            #pragma unroll
            for (int j = 0; j < 4; ++j)
                #pragma unroll
                for (int i = 0; i < 4; ++i) r[j][i] = rN[j][i];
            #pragma unroll
            for (int sub = 0; sub < 2; ++sub)
                #pragma unroll
                for (int t = 0; t < 2; ++t) bfr[sub][t] = bN[sub][t];
        }
    }

    // ---- epilogue: flat per-thread fragment store (coalesced) ----
    unsigned short* pb = part2 + (((size_t)(kt * NSPLITS + split)) * 256 + tid) * 32;
    #pragma unroll
    for (int s = 0; s < 4; ++s) {
        bf16x8 v;
        #pragma unroll
        for (int e = 0; e < 4; ++e) {
            v[e]     = f2bf(acc[s][0][e]);
            v[e + 4] = f2bf(acc[s][1][e]);
        }
        *reinterpret_cast<bf16x8*>(pb + s * 8) = v;
    }
}

// ---------------- reduce stage 1: 200 -> 8 (coalesced reads) -----------------
__global__ __launch_bounds__(256) void k_reduce1(
    const unsigned short* __restrict__ part2, float* __restrict__ part3)
{
    const int q  = blockIdx.x * 256 + threadIdx.x;   // 0..16383
    const int pg = blockIdx.y;                       // 0..7
    const int kt = q >> 11;
    const int tp = (q >> 3) & 255;
    const int sl = q & 7;
    f32x4 s; s[0] = s[1] = s[2] = s[3] = 0.f;
    const int pend = pg * 25 + 25;
    for (int p = pg * 25; p < pend; ++p) {
        s16x4 v = *reinterpret_cast<const s16x4*>(
            part2 + (((size_t)(kt * NSPLITS + p)) * 256 + tp) * 32 + sl * 4);
        s[0] += bf2f((unsigned short)v[0]); s[1] += bf2f((unsigned short)v[1]);
        s[2] += bf2f((unsigned short)v[2]); s[3] += bf2f((unsigned short)v[3]);
    }
    *reinterpret_cast<f32x4*>(part3 + ((size_t)pg * 16384 + q) * 4) = s;
}

// ---------------- reduce stage 2: 8 -> 1, fold g, emit specbfa ---------------
// specbfa[ft16(8)][kt32(16)][lane][8]: [ft][kt][16h+m][j] = spec[ft*16+m][kt*32+8h+j]
__global__ __launch_bounds__(256) void k_reduce2(
    const float* __restrict__ part3, const float* __restrict__ g,
    unsigned short* __restrict__ specbfa)
{
    const int q = blockIdx.x * 256 + threadIdx.x;    // 0..16383
    f32x4 s; s[0] = s[1] = s[2] = s[3] = 0.f;
    #pragma unroll
    for (int pg = 0; pg < 8; ++pg) {
        f32x4 v = *reinterpret_cast<const f32x4*>(part3 + ((size_t)pg * 16384 + q) * 4);
        s[0] += v[0]; s[1] += v[1]; s[2] += v[2]; s[3] += v[3];
    }
    const int kt = q >> 11, tp = (q >> 3) & 255, sl = q & 7;
    const int wid = tp >> 6, le = tp & 63, hh = le >> 4, mm = le & 15;
    const int ss = sl >> 1, tt = sl & 1;
    const int f = wid * 32 + tt * 16 + mm;
    const int k = kt * 64 + ss * 16 + hh * 4;
    f32x4 gv = *reinterpret_cast<const f32x4*>(g + k);
    s16x4 o;
    #pragma unroll
    for (int e = 0; e < 4; ++e) o[e] = f2bf(s[e] * gv[e]);
    const int lanep = ((k >> 3) & 3) * 16 + (f & 15);
    size_t ad = ((size_t)((f >> 4) * 16 + (k >> 5)) * 64 + lanep) * 8 + (k & 7);
    *reinterpret_cast<s16x4*>(specbfa + ad) = o;
}

// ---------------- GEMM2: fragment-contiguous streams + relu ------------------
__global__ __launch_bounds__(256) void k_out_bf(
    const unsigned short* __restrict__ Ubfa,
    const unsigned short* __restrict__ specbfa,
    float* __restrict__ out)
{
    const int tid  = threadIdx.x;
    const int wid  = tid >> 6;
    const int lane = tid & 63;
    const int h = lane >> 4, m = lane & 15;
    const int wr = wid >> 1, wc = wid & 1;
    const int nbase = blockIdx.x * 64 + wr * 32;
    const int fbase = wc * 64;

    // fragment stride: 64 lanes * 8 = 512 elems; per-nt/ft stride = 16*512 = 8192
    const unsigned short* Al[2];
    #pragma unroll
    for (int i = 0; i < 2; ++i)
        Al[i] = Ubfa + ((size_t)((nbase >> 4) + i) * 8192 + lane * 8);
    const unsigned short* Blp[4];
    #pragma unroll
    for (int t = 0; t < 4; ++t)
        Blp[t] = specbfa + ((size_t)(4 * wc + t) * 8192 + lane * 8);

    f32x4 acc[2][4];
    #pragma unroll
    for (int i = 0; i < 2; ++i)
        #pragma unroll
        for (int t = 0; t < 4; ++t)
            #pragma unroll
            for (int e = 0; e < 4; ++e) acc[i][t][e] = 0.f;

    bf16x8 aC[2], bC[4];
    #pragma unroll
    for (int i = 0; i < 2; ++i) aC[i] = *reinterpret_cast<const bf16x8*>(Al[i]);
    #pragma unroll
    for (int t = 0; t < 4; ++t) bC[t] = *reinterpret_cast<const bf16x8*>(Blp[t]);

    for (int kb = 0; kb < 16; ++kb) {         // kt32 steps
        int kn = (kb + 1 < 16) ? kb + 1 : 0;  // clamp; last load unused
        bf16x8 aN[2], bN[4];
        #pragma unroll
        for (int i = 0; i < 2; ++i)
            aN[i] = *reinterpret_cast<const bf16x8*>(Al[i] + (size_t)kn * 512);
        #pragma unroll
        for (int t = 0; t < 4; ++t)
            bN[t] = *reinterpret_cast<const bf16x8*>(Blp[t] + (size_t)kn * 512);

        #pragma unroll
        for (int i = 0; i < 2; ++i)
            #pragma unroll
            for (int t = 0; t < 4; ++t)
                acc[i][t] = __builtin_amdgcn_mfma_f32_16x16x32_bf16(
                    aC[i], bC[t], acc[i][t], 0, 0, 0);

        #pragma unroll
        for (int i = 0; i < 2; ++i) aC[i] = aN[i];
        #pragma unroll
        for (int t = 0; t < 4; ++t) bC[t] = bN[t];
    }

    #pragma unroll
    for (int i = 0; i < 2; ++i)
        #pragma unroll
        for (int r = 0; r < 4; ++r) {
            int nn = nbase + 16 * i + 4 * h + r;
            if (nn < N_NODES) {
                float* orow = out + (long)nn * F_DIM + fbase + m;
                #pragma unroll
                for (int t = 0; t < 4; ++t)
                    orow[16 * t] = fmaxf(acc[i][t][r], 0.f);
            }
        }
}

// =================== deep fallback (round-1) if ws tiny ======================
__global__ __launch_bounds__(256) void k_spec_v1(
    const float* __restrict__ U, const float* __restrict__ g,
    const float* __restrict__ x, float* __restrict__ specT)
{
    const int kt    = blockIdx.x;
    const int split = blockIdx.y;
    const int tid   = threadIdx.x;
    const int wid   = tid >> 6;
    const int lane  = tid & 63;
    const int h     = lane >> 4;
    const int m     = lane & 15;
    const int k0 = kt * 64;
    const int f0 = wid * 32;
    const int chunk1 = 782;
    const int n_start = split * chunk1;
    int n_end = n_start + chunk1;
    if (n_end > N_NODES) n_end = N_NODES;

    f32x4 acc[4][2];
    #pragma unroll
    for (int s = 0; s < 4; ++s)
        #pragma unroll
        for (int t = 0; t < 2; ++t)
            #pragma unroll
            for (int e = 0; e < 4; ++e) acc[s][t][e] = 0.f;

    for (int nb = n_start; nb < n_end; nb += 32) {
        bf16x8 a[4]; bf16x8 b[2];
        const int nrow = nb + 8 * h;
        #pragma unroll
        for (int j = 0; j < 8; ++j) {
            int nn = nrow + j;
            bool valid = (nn < n_end);
            int nc = valid ? nn : (n_end - 1);
            const float* Urow = U + (long)nc * K_EIG + k0 + m;
            const float* Xrow = x + (long)nc * F_DIM + f0 + m;
            #pragma unroll
            for (int s = 0; s < 4; ++s) {
                short bv = f2bf(Urow[16 * s]);
                a[s][j] = valid ? bv : (short)0;
            }
            #pragma unroll
            for (int t = 0; t < 2; ++t) {
                short bv = f2bf(Xrow[16 * t]);
                b[t][j] = valid ? bv : (short)0;
            }
        }
        #pragma unroll
        for (int s = 0; s < 4; ++s)
            #pragma unroll
            for (int t = 0; t < 2; ++t)
                acc[s][t] = __builtin_amdgcn_mfma_f32_16x16x32_bf16(
                    a[s], b[t], acc[s][t], 0, 0, 0);
    }
    #pragma unroll
    for (int s = 0; s < 4; ++s)
        #pragma unroll
        for (int t = 0; t < 2; ++t)
            #pragma unroll
            for (int r = 0; r < 4; ++r) {
                int k = k0 + 16 * s + 4 * h + r;
                int f = f0 + 16 * t + m;
                atomicAdd(&specT[(long)f * K_EIG + k], acc[s][t][r] * g[k]);
            }
}

__global__ __launch_bounds__(256) void k_out_v1(
    const float* __restrict__ U, const float* __restrict__ specT,
    float* __restrict__ out)
{
    const int tid  = threadIdx.x;
    const int wid  = tid >> 6;
    const int lane = tid & 63;
    const int h = lane >> 4, m = lane & 15;
    const int wr = wid >> 1, wc = wid & 1;
    const int nbase = blockIdx.x * 128 + wr * 64;
    const int fbase = wc * 64;

    f32x4 acc[4][4];
    #pragma unroll
    for (int i = 0; i < 4; ++i)
        #pragma unroll
        for (int t = 0; t < 4; ++t)
            #pragma unroll
            for (int e = 0; e < 4; ++e) acc[i][t][e] = 0.f;

    for (int kb = 0; kb < K_EIG; kb += 32) {
        bf16x8 a[4], b[4];
        #pragma unroll
        for (int i = 0; i < 4; ++i) {
            int nn = nbase + 16 * i + m;
            bool valid = (nn < N_NODES);
            int nc = valid ? nn : (N_NODES - 1);
            const f32x4* p = reinterpret_cast<const f32x4*>(
                U + (long)nc * K_EIG + kb + 8 * h);
            f32x4 lo = p[0], hi = p[1];
            #pragma unroll
            for (int j = 0; j < 4; ++j) {
                short b0 = f2bf(lo[j]), b1 = f2bf(hi[j]);
                a[i][j]     = valid ? b0 : (short)0;
                a[i][j + 4] = valid ? b1 : (short)0;
            }
        }
        #pragma unroll
        for (int t = 0; t < 4; ++t) {
            const f32x4* p = reinterpret_cast<const f32x4*>(
                specT + (long)(fbase + 16 * t + m) * K_EIG + kb + 8 * h);
            f32x4 lo = p[0], hi = p[1];
            #pragma unroll
            for (int j = 0; j < 4; ++j) {
                b[t][j]     = f2bf(lo[j]);
                b[t][j + 4] = f2bf(hi[j]);
            }
        }
        #pragma unroll
        for (int i = 0; i < 4; ++i)
            #pragma unroll
            for (int t = 0; t < 4; ++t)
                acc[i][t] = __builtin_amdgcn_mfma_f32_16x16x32_bf16(
                    a[i], b[t], acc[i][t], 0, 0, 0);
    }
    #pragma unroll
    for (int i = 0; i < 4; ++i)
        #pragma unroll
        for (int r = 0; r < 4; ++r) {
            int nn = nbase + 16 * i + 4 * h + r;
            if (nn < N_NODES) {
                float* orow = out + (long)nn * F_DIM + fbase + m;
                #pragma unroll
                for (int t = 0; t < 4; ++t)
                    orow[16 * t] = fmaxf(acc[i][t][r], 0.f);
            }
        }
}

// ============================================================================
extern "C" void kernel_launch(void* const* d_in, const int* in_sizes, int n_in,
                              void* d_out, int out_size, void* d_ws, size_t ws_size,
                              hipStream_t stream) {
    const float* U = (const float*)d_in[0];
    const float* g = (const float*)d_in[1];
    const float* x = (const float*)d_in[2];
    float* out = (float*)d_out;

    // ws layout (bytes)
    const size_t OFF_XTA   = 0;                 // 8*1600*64*8*2     = 13,107,200
    const size_t OFF_PART  = 13107200;          // 8*200*256*32*2    = 26,214,400
    const size_t OFF_SPECA = 39321600;          // 8*16*64*8*2       =    131,072
    const size_t OFF_UBFA  = 39452672;          // 3136*16*64*8*2    = 51,380,224
    const size_t OFF_PART3 = 90832896;          // 8*16384*4*4       =  2,097,152
    const size_t WS_NEEDED = 92930048;

    if (ws_size >= WS_NEEDED) {
        unsigned short* xTa     = (unsigned short*)((char*)d_ws + OFF_XTA);
        unsigned short* part2   = (unsigned short*)((char*)d_ws + OFF_PART);
        unsigned short* specbfa = (unsigned short*)((char*)d_ws + OFF_SPECA);
        unsigned short* Ubfa    = (unsigned short*)((char*)d_ws + OFF_UBFA);
        float*          part3   = (float*)((char*)d_ws + OFF_PART3);

        dim3 gx(NPAD / 64, F_DIM / 64);   // 800 x 2
        prep_x<<<gx, 256, 0, stream>>>(x, xTa);

        dim3 g1(K_EIG / 64, NSPLITS);     // 8 x 200 = 1600 blocks
        k_spec_f<<<g1, 256, 0, stream>>>(U, xTa, Ubfa, part2);

        dim3 gr1(64, 8);                  // 512 blocks
        k_reduce1<<<gr1, 256, 0, stream>>>(part2, part3);
        k_reduce2<<<64, 256, 0, stream>>>(part3, g, specbfa);

        int nb2 = (N_NODES + 63) / 64;    // 782
        k_out_bf<<<nb2, 256, 0, stream>>>(Ubfa, specbfa, out);
    } else {
        float* specT = (float*)d_ws;      // 256 KB
        hipMemsetAsync(specT, 0, (size_t)K_EIG * F_DIM * sizeof(float), stream);
        dim3 g1(K_EIG / 64, 64);
        k_spec_v1<<<g1, 256, 0, stream>>>(U, g, x, specT);
        int nb2 = (N_NODES + 127) / 128;
        k_out_v1<<<nb2, 256, 0, stream>>>(U, specT, out);
    }
}